// Round 4
// baseline (181.217 us; speedup 1.0000x reference)
//
#include <hip/hip_runtime.h>

#define BINS 10
#define BLOCK 256
#define GRID 2048

// ---------------------------------------------------------------------------
// Pass 1: fused histogram + per-bin smooth-L1 loss sums.
// LDS per-thread-column histogram with FIRE-AND-FORGET LDS atomics:
// atomicAdd on __shared__ float (return unused) -> ds_add_f32, no
// read-modify-write dependency chain. Each thread owns column t of
// hc[bin][t]/hs[bin][t]; 4-byte stride -> 2 lanes/bank (conflict-free).
// GRID=2048 -> 8 blocks/CU (LDS-limited exactly), 32 waves/CU of TLP.
// ---------------------------------------------------------------------------
__global__ __launch_bounds__(BLOCK) void ghmr_histo_kernel(
    const float* __restrict__ pred,
    const float* __restrict__ target,
    float2* __restrict__ part,   // [BINS][nblk] {cnt, sum}
    int n)
{
    __shared__ float hc[BINS][BLOCK];
    __shared__ float hs[BINS][BLOCK];
    const int t = threadIdx.x;
#pragma unroll
    for (int b = 0; b < BINS; ++b) { hc[b][t] = 0.0f; hs[b][t] = 0.0f; }
    __syncthreads();

    const float INV180 = 1.0f / 180.0f;   // mul, not div (matched ref in R2/R3, absmax 0.0)
    const int tid    = blockIdx.x * BLOCK + t;
    const int stride = gridDim.x * BLOCK;
    const int n4     = n >> 2;

    const float4* p4 = reinterpret_cast<const float4*>(pred);
    const float4* t4 = reinterpret_cast<const float4*>(target);

    for (int i = tid; i < n4; i += stride) {
        float4 p = p4[i];
        float4 q = t4[i];
        float pe[4] = {p.x, p.y, p.z, p.w};
        float te[4] = {q.x, q.y, q.z, q.w};
#pragma unroll
        for (int k = 0; k < 4; ++k) {
            float d  = pe[k] - te[k];
            float ad = fabsf(d);
            float wd = fminf(ad, 360.0f - ad);   // wrapped to [0,180]
            float g  = wd * INV180;              // ref: diff/180
            float gg = g * 10.0f;                // ref: g*BINS
            int idx  = (int)gg;                  // gg>=0 -> trunc == floor
            idx = min(max(idx, 0), BINS - 1);
            float ls = (ad < 1.0f) ? (0.5f * d * d) : (ad - 0.5f);  // smooth L1, mu=1
            atomicAdd(&hc[idx][t], 1.0f);        // ds_add_f32, fire-and-forget
            atomicAdd(&hs[idx][t], ls);          // ds_add_f32
        }
    }
    // scalar tail (n % 4), generic safety
    for (int i = (n4 << 2) + tid; i < n; i += stride) {
        float d  = pred[i] - target[i];
        float ad = fabsf(d);
        float wd = fminf(ad, 360.0f - ad);
        float g  = wd * INV180;
        float gg = g * 10.0f;
        int idx  = (int)gg;
        idx = min(max(idx, 0), BINS - 1);
        float ls = (ad < 1.0f) ? (0.5f * d * d) : (ad - 0.5f);
        atomicAdd(&hc[idx][t], 1.0f);
        atomicAdd(&hs[idx][t], ls);
    }
    __syncthreads();   // barrier drains lgkmcnt -> all ds_add_f32 landed

    // Block epilogue: 160 threads, thread (r=t>>4, j=t&15) sums 16 columns
    // stride-16, then 16-lane shuffle tree. One float2 store per bin.
    if (t < 16 * BINS) {
        const int r = t >> 4;
        const int j = t & 15;
        float c = 0.0f, s = 0.0f;
#pragma unroll
        for (int k = 0; k < 16; ++k) {
            c += hc[r][j + 16 * k];
            s += hs[r][j + 16 * k];
        }
#pragma unroll
        for (int off = 8; off > 0; off >>= 1) {
            c += __shfl_down(c, off, 16);
            s += __shfl_down(s, off, 16);
        }
        if (j == 0) part[r * gridDim.x + blockIdx.x] = make_float2(c, s);
    }
}

// ---------------------------------------------------------------------------
// Pass 2: reduce partials (one wave per bin, coalesced float2) + weight math.
// Separate kernel launch = free device-wide memory fence (no coherence
// subtleties vs a last-block pattern).
// ---------------------------------------------------------------------------
__global__ __launch_bounds__(64 * BINS) void ghmr_reduce_final(
    const float2* __restrict__ part,
    const float*  __restrict__ acc_sum,
    float* __restrict__ out,
    float total, int nblk)
{
    const int w    = threadIdx.x >> 6;   // bin 0..9
    const int lane = threadIdx.x & 63;

    float csum = 0.0f, ssum = 0.0f;
    const float2* pw = part + (size_t)w * nblk;
    for (int i = lane; i < nblk; i += 64) {
        float2 v = pw[i];
        csum += v.x;
        ssum += v.y;
    }
#pragma unroll
    for (int off = 32; off > 0; off >>= 1) {
        csum += __shfl_down(csum, off, 64);
        ssum += __shfl_down(ssum, off, 64);
    }

    __shared__ float C[BINS];
    __shared__ float S[BINS];
    if (lane == 0) { C[w] = csum; S[w] = ssum; }
    __syncthreads();

    if (threadIdx.x == 0) {
        float acc_new[BINS];
        int n_nonempty = 0;
#pragma unroll
        for (int b = 0; b < BINS; ++b) {
            float cnt = C[b];
            bool ne = (cnt > 0.0f);
            acc_new[b] = ne ? (0.9f * acc_sum[b] + 0.1f * cnt) : acc_sum[b];
            n_nonempty += ne ? 1 : 0;
        }
        float n_safe = fmaxf((float)n_nonempty, 1.0f);

        double weighted = 0.0;
        double plain    = 0.0;
#pragma unroll
        for (int b = 0; b < BINS; ++b) {
            float wb = (acc_new[b] > 0.0f)
                           ? (total / (n_safe * fmaxf(acc_new[b], 1e-30f)))
                           : 0.0f;
            float wp = powf(wb, 0.75f);
            weighted += (double)S[b] * (double)wp;
            plain    += (double)S[b];
        }
        double res = ((n_nonempty > 0) ? weighted : plain) / (double)total;
        out[0] = (float)res;
    }
}

extern "C" void kernel_launch(void* const* d_in, const int* in_sizes, int n_in,
                              void* d_out, int out_size, void* d_ws, size_t ws_size,
                              hipStream_t stream) {
    const float* pred    = (const float*)d_in[0];
    const float* target  = (const float*)d_in[1];
    const float* acc_sum = (const float*)d_in[2];
    float* out = (float*)d_out;
    const int n = in_sizes[0];

    int nblk = GRID;
    size_t need = (size_t)BINS * (size_t)nblk * sizeof(float2);
    if (ws_size < need) {
        nblk = (int)(ws_size / ((size_t)BINS * sizeof(float2)));
        if (nblk < 1) nblk = 1;
    }

    float2* part = (float2*)d_ws;   // [BINS][nblk]

    ghmr_histo_kernel<<<nblk, BLOCK, 0, stream>>>(pred, target, part, n);
    ghmr_reduce_final<<<1, 64 * BINS, 0, stream>>>(part, acc_sum, out, (float)n, nblk);
}

// Round 7
// 106.454 us; speedup vs baseline: 1.7023x; 1.7023x over previous
//
#include <hip/hip_runtime.h>

#define BINS 10
#define BLOCK 256
#define GRID 2048   // 8 blocks/CU (LDS 20KB x 8 = 160KB exactly) -> 32 waves/CU

// ---------------------------------------------------------------------------
// Pass 1: fused histogram + per-bin smooth-L1 loss sums.
// R3 structure (best measured): LDS per-thread-column float2 RMW —
// ds_read_b64 + 2 VALU + ds_write_b64 per element, each thread owns its
// column (no conflicts, no atomics; LDS atomics measured 2.5x WORSE in R4:
// DS-pipe throughput-bound at 4% VALUBusy). Change vs R3: GRID 1024->2048
// doubles waves/CU (16->32) to overlap the per-wave RMW latency chain.
// ---------------------------------------------------------------------------
__global__ __launch_bounds__(BLOCK) void ghmr_histo_kernel(
    const float* __restrict__ pred,
    const float* __restrict__ target,
    float2* __restrict__ part,   // [BINS][nblk] {cnt, sum}
    int n)
{
    __shared__ float2 h[BINS][BLOCK];
    const int t = threadIdx.x;
#pragma unroll
    for (int b = 0; b < BINS; ++b) h[b][t] = make_float2(0.0f, 0.0f);
    __syncthreads();

    const float INV180 = 1.0f / 180.0f;   // mul form matched ref (absmax 0.0 in R2-R4)
    const int tid    = blockIdx.x * BLOCK + t;
    const int stride = gridDim.x * BLOCK;
    const int n4     = n >> 2;

    const float4* p4 = reinterpret_cast<const float4*>(pred);
    const float4* t4 = reinterpret_cast<const float4*>(target);

    for (int i = tid; i < n4; i += stride) {
        float4 p = p4[i];
        float4 q = t4[i];
        float pe[4] = {p.x, p.y, p.z, p.w};
        float te[4] = {q.x, q.y, q.z, q.w};
#pragma unroll
        for (int k = 0; k < 4; ++k) {
            float d  = pe[k] - te[k];
            float ad = fabsf(d);
            float wd = fminf(ad, 360.0f - ad);   // wrapped to [0,180]
            float g  = wd * INV180;              // ref: diff/180
            float gg = g * 10.0f;                // ref: g*BINS
            int idx  = (int)gg;                  // gg>=0 -> trunc == floor
            idx = min(max(idx, 0), BINS - 1);
            float ls = (ad < 1.0f) ? (0.5f * d * d) : (ad - 0.5f);  // smooth L1, mu=1
            float2 v = h[idx][t];
            v.x += 1.0f;
            v.y += ls;
            h[idx][t] = v;
        }
    }
    // scalar tail (n % 4), generic safety
    for (int i = (n4 << 2) + tid; i < n; i += stride) {
        float d  = pred[i] - target[i];
        float ad = fabsf(d);
        float wd = fminf(ad, 360.0f - ad);
        float g  = wd * INV180;
        float gg = g * 10.0f;
        int idx  = (int)gg;
        idx = min(max(idx, 0), BINS - 1);
        float ls = (ad < 1.0f) ? (0.5f * d * d) : (ad - 0.5f);
        float2 v = h[idx][t];
        v.x += 1.0f;
        v.y += ls;
        h[idx][t] = v;
    }
    __syncthreads();

    // Block epilogue: 160 threads, thread (r=t>>4, j=t&15) sums 16 columns
    // stride-16, then 16-lane shuffle tree. One float2 store per bin.
    if (t < 16 * BINS) {
        const int r = t >> 4;
        const int j = t & 15;
        float c = 0.0f, s = 0.0f;
#pragma unroll
        for (int k = 0; k < 16; ++k) {
            float2 v = h[r][j + 16 * k];
            c += v.x;
            s += v.y;
        }
#pragma unroll
        for (int off = 8; off > 0; off >>= 1) {
            c += __shfl_down(c, off, 16);
            s += __shfl_down(s, off, 16);
        }
        if (j == 0) part[r * gridDim.x + blockIdx.x] = make_float2(c, s);
    }
}

// ---------------------------------------------------------------------------
// Pass 2: reduce partials (one wave per bin, coalesced float2) + weight math.
// ---------------------------------------------------------------------------
__global__ __launch_bounds__(64 * BINS) void ghmr_reduce_final(
    const float2* __restrict__ part,
    const float*  __restrict__ acc_sum,
    float* __restrict__ out,
    float total, int nblk)
{
    const int w    = threadIdx.x >> 6;   // bin 0..9
    const int lane = threadIdx.x & 63;

    float csum = 0.0f, ssum = 0.0f;
    const float2* pw = part + (size_t)w * nblk;
    for (int i = lane; i < nblk; i += 64) {
        float2 v = pw[i];
        csum += v.x;
        ssum += v.y;
    }
#pragma unroll
    for (int off = 32; off > 0; off >>= 1) {
        csum += __shfl_down(csum, off, 64);
        ssum += __shfl_down(ssum, off, 64);
    }

    __shared__ float C[BINS];
    __shared__ float S[BINS];
    if (lane == 0) { C[w] = csum; S[w] = ssum; }
    __syncthreads();

    if (threadIdx.x == 0) {
        float acc_new[BINS];
        int n_nonempty = 0;
#pragma unroll
        for (int b = 0; b < BINS; ++b) {
            float cnt = C[b];
            bool ne = (cnt > 0.0f);
            acc_new[b] = ne ? (0.9f * acc_sum[b] + 0.1f * cnt) : acc_sum[b];
            n_nonempty += ne ? 1 : 0;
        }
        float n_safe = fmaxf((float)n_nonempty, 1.0f);

        double weighted = 0.0;
        double plain    = 0.0;
#pragma unroll
        for (int b = 0; b < BINS; ++b) {
            float wb = (acc_new[b] > 0.0f)
                           ? (total / (n_safe * fmaxf(acc_new[b], 1e-30f)))
                           : 0.0f;
            float wp = powf(wb, 0.75f);
            weighted += (double)S[b] * (double)wp;
            plain    += (double)S[b];
        }
        double res = ((n_nonempty > 0) ? weighted : plain) / (double)total;
        out[0] = (float)res;
    }
}

extern "C" void kernel_launch(void* const* d_in, const int* in_sizes, int n_in,
                              void* d_out, int out_size, void* d_ws, size_t ws_size,
                              hipStream_t stream) {
    const float* pred    = (const float*)d_in[0];
    const float* target  = (const float*)d_in[1];
    const float* acc_sum = (const float*)d_in[2];
    float* out = (float*)d_out;
    const int n = in_sizes[0];

    int nblk = GRID;
    size_t need = (size_t)BINS * (size_t)nblk * sizeof(float2);
    if (ws_size < need) {
        nblk = (int)(ws_size / ((size_t)BINS * sizeof(float2)));
        if (nblk < 1) nblk = 1;
    }

    float2* part = (float2*)d_ws;   // [BINS][nblk]

    ghmr_histo_kernel<<<nblk, BLOCK, 0, stream>>>(pred, target, part, n);
    ghmr_reduce_final<<<1, 64 * BINS, 0, stream>>>(part, acc_sum, out, (float)n, nblk);
}

// Round 9
// 105.568 us; speedup vs baseline: 1.7166x; 1.0084x over previous
//
#include <hip/hip_runtime.h>

#define BINS 10
#define BLOCK 256
#define GRID 1024   // 4 blocks/CU. Measured best: R3(1024)=102.2us vs R7(2048)=106.5us.

// ---------------------------------------------------------------------------
// Pass 1: fused histogram + per-bin smooth-L1 loss sums.
// Best-measured structure (R3): LDS per-thread-column float2 RMW —
// ds_read_b64 + 2 VALU + ds_write_b64 per element, each thread owns its
// column (no conflicts, no atomics; LDS atomics measured 2.5x WORSE in R4:
// DS-pipe serialization at 4% VALUBusy). Change vs R3: 2 independent
// float4 pairs per loop iteration (8 elems) for deeper MLP.
// ---------------------------------------------------------------------------
__global__ __launch_bounds__(BLOCK) void ghmr_histo_kernel(
    const float* __restrict__ pred,
    const float* __restrict__ target,
    float2* __restrict__ part,   // [BINS][nblk] {cnt, sum}
    int n)
{
    __shared__ float2 h[BINS][BLOCK];
    const int t = threadIdx.x;
#pragma unroll
    for (int b = 0; b < BINS; ++b) h[b][t] = make_float2(0.0f, 0.0f);
    __syncthreads();

    const float INV180 = 1.0f / 180.0f;   // mul form matched ref (absmax 0.0 R2-R4,R7)
    const int tid    = blockIdx.x * BLOCK + t;
    const int stride = gridDim.x * BLOCK;
    const int n4     = n >> 2;

    const float4* p4 = reinterpret_cast<const float4*>(pred);
    const float4* t4 = reinterpret_cast<const float4*>(target);

    int i = tid;
    // paired iterations: two independent float4 loads in flight
    for (; i + stride < n4; i += 2 * stride) {
        float4 pa = p4[i];
        float4 qa = t4[i];
        float4 pb = p4[i + stride];
        float4 qb = t4[i + stride];
        float pe[8] = {pa.x, pa.y, pa.z, pa.w, pb.x, pb.y, pb.z, pb.w};
        float te[8] = {qa.x, qa.y, qa.z, qa.w, qb.x, qb.y, qb.z, qb.w};
#pragma unroll
        for (int k = 0; k < 8; ++k) {
            float d  = pe[k] - te[k];
            float ad = fabsf(d);
            float wd = fminf(ad, 360.0f - ad);   // wrapped to [0,180]
            float g  = wd * INV180;              // ref: diff/180
            float gg = g * 10.0f;                // ref: g*BINS
            int idx  = (int)gg;                  // gg>=0 -> trunc == floor
            idx = min(max(idx, 0), BINS - 1);
            float ls = (ad < 1.0f) ? (0.5f * d * d) : (ad - 0.5f);  // smooth L1, mu=1
            float2 v = h[idx][t];
            v.x += 1.0f;
            v.y += ls;
            h[idx][t] = v;
        }
    }
    // leftover single float4 iteration(s)
    for (; i < n4; i += stride) {
        float4 p = p4[i];
        float4 q = t4[i];
        float pe[4] = {p.x, p.y, p.z, p.w};
        float te[4] = {q.x, q.y, q.z, q.w};
#pragma unroll
        for (int k = 0; k < 4; ++k) {
            float d  = pe[k] - te[k];
            float ad = fabsf(d);
            float wd = fminf(ad, 360.0f - ad);
            float g  = wd * INV180;
            float gg = g * 10.0f;
            int idx  = (int)gg;
            idx = min(max(idx, 0), BINS - 1);
            float ls = (ad < 1.0f) ? (0.5f * d * d) : (ad - 0.5f);
            float2 v = h[idx][t];
            v.x += 1.0f;
            v.y += ls;
            h[idx][t] = v;
        }
    }
    // scalar tail (n % 4), generic safety
    for (int j = (n4 << 2) + tid; j < n; j += stride) {
        float d  = pred[j] - target[j];
        float ad = fabsf(d);
        float wd = fminf(ad, 360.0f - ad);
        float g  = wd * INV180;
        float gg = g * 10.0f;
        int idx  = (int)gg;
        idx = min(max(idx, 0), BINS - 1);
        float ls = (ad < 1.0f) ? (0.5f * d * d) : (ad - 0.5f);
        float2 v = h[idx][t];
        v.x += 1.0f;
        v.y += ls;
        h[idx][t] = v;
    }
    __syncthreads();

    // Block epilogue: 160 threads, thread (r=t>>4, j=t&15) sums 16 columns
    // stride-16, then 16-lane shuffle tree. One float2 store per bin.
    if (t < 16 * BINS) {
        const int r = t >> 4;
        const int j = t & 15;
        float c = 0.0f, s = 0.0f;
#pragma unroll
        for (int k = 0; k < 16; ++k) {
            float2 v = h[r][j + 16 * k];
            c += v.x;
            s += v.y;
        }
#pragma unroll
        for (int off = 8; off > 0; off >>= 1) {
            c += __shfl_down(c, off, 16);
            s += __shfl_down(s, off, 16);
        }
        if (j == 0) part[r * gridDim.x + blockIdx.x] = make_float2(c, s);
    }
}

// ---------------------------------------------------------------------------
// Pass 2: reduce partials (one wave per bin, coalesced float2) + weight math.
// ---------------------------------------------------------------------------
__global__ __launch_bounds__(64 * BINS) void ghmr_reduce_final(
    const float2* __restrict__ part,
    const float*  __restrict__ acc_sum,
    float* __restrict__ out,
    float total, int nblk)
{
    const int w    = threadIdx.x >> 6;   // bin 0..9
    const int lane = threadIdx.x & 63;

    float csum = 0.0f, ssum = 0.0f;
    const float2* pw = part + (size_t)w * nblk;
    for (int i = lane; i < nblk; i += 64) {
        float2 v = pw[i];
        csum += v.x;
        ssum += v.y;
    }
#pragma unroll
    for (int off = 32; off > 0; off >>= 1) {
        csum += __shfl_down(csum, off, 64);
        ssum += __shfl_down(ssum, off, 64);
    }

    __shared__ float C[BINS];
    __shared__ float S[BINS];
    if (lane == 0) { C[w] = csum; S[w] = ssum; }
    __syncthreads();

    if (threadIdx.x == 0) {
        float acc_new[BINS];
        int n_nonempty = 0;
#pragma unroll
        for (int b = 0; b < BINS; ++b) {
            float cnt = C[b];
            bool ne = (cnt > 0.0f);
            acc_new[b] = ne ? (0.9f * acc_sum[b] + 0.1f * cnt) : acc_sum[b];
            n_nonempty += ne ? 1 : 0;
        }
        float n_safe = fmaxf((float)n_nonempty, 1.0f);

        double weighted = 0.0;
        double plain    = 0.0;
#pragma unroll
        for (int b = 0; b < BINS; ++b) {
            float wb = (acc_new[b] > 0.0f)
                           ? (total / (n_safe * fmaxf(acc_new[b], 1e-30f)))
                           : 0.0f;
            float wp = powf(wb, 0.75f);
            weighted += (double)S[b] * (double)wp;
            plain    += (double)S[b];
        }
        double res = ((n_nonempty > 0) ? weighted : plain) / (double)total;
        out[0] = (float)res;
    }
}

extern "C" void kernel_launch(void* const* d_in, const int* in_sizes, int n_in,
                              void* d_out, int out_size, void* d_ws, size_t ws_size,
                              hipStream_t stream) {
    const float* pred    = (const float*)d_in[0];
    const float* target  = (const float*)d_in[1];
    const float* acc_sum = (const float*)d_in[2];
    float* out = (float*)d_out;
    const int n = in_sizes[0];

    int nblk = GRID;
    size_t need = (size_t)BINS * (size_t)nblk * sizeof(float2);
    if (ws_size < need) {
        nblk = (int)(ws_size / ((size_t)BINS * sizeof(float2)));
        if (nblk < 1) nblk = 1;
    }

    float2* part = (float2*)d_ws;   // [BINS][nblk]

    ghmr_histo_kernel<<<nblk, BLOCK, 0, stream>>>(pred, target, part, n);
    ghmr_reduce_final<<<1, 64 * BINS, 0, stream>>>(part, acc_sum, out, (float)n, nblk);
}

// Round 13
// 103.390 us; speedup vs baseline: 1.7527x; 1.0211x over previous
//
#include <hip/hip_runtime.h>

#define BINS 10
#define BLOCK 256
#define GRID 1024   // 4 blocks/CU — best measured (R3=102.2us; 2048 was 106.5us)

// ---------------------------------------------------------------------------
// Pass 1: fused histogram + per-bin smooth-L1 loss sums.
// Best-measured structure (R3, 102.2us total): LDS per-thread-column float2
// RMW — ds_read_b64 + 2 VALU + ds_write_b64 per element, each thread owns
// its column (no conflicts, no atomics). Measured alternatives: LDS atomics
// 2.5x worse (R4, DS-pipe serialization); GRID 2048 +4us (R7); paired-load
// MLP +3us (R9); register one-hot +12us (R2).
// ---------------------------------------------------------------------------
__global__ __launch_bounds__(BLOCK) void ghmr_histo_kernel(
    const float* __restrict__ pred,
    const float* __restrict__ target,
    float2* __restrict__ part,   // [BINS][nblk] {cnt, sum}
    int n)
{
    __shared__ float2 h[BINS][BLOCK];
    const int t = threadIdx.x;
#pragma unroll
    for (int b = 0; b < BINS; ++b) h[b][t] = make_float2(0.0f, 0.0f);
    __syncthreads();

    const float INV180 = 1.0f / 180.0f;   // mul form matched ref (absmax 0.0 all rounds)
    const int tid    = blockIdx.x * BLOCK + t;
    const int stride = gridDim.x * BLOCK;
    const int n4     = n >> 2;

    const float4* p4 = reinterpret_cast<const float4*>(pred);
    const float4* t4 = reinterpret_cast<const float4*>(target);

    for (int i = tid; i < n4; i += stride) {
        float4 p = p4[i];
        float4 q = t4[i];
        float pe[4] = {p.x, p.y, p.z, p.w};
        float te[4] = {q.x, q.y, q.z, q.w};
#pragma unroll
        for (int k = 0; k < 4; ++k) {
            float d  = pe[k] - te[k];
            float ad = fabsf(d);
            float wd = fminf(ad, 360.0f - ad);   // wrapped to [0,180]
            float g  = wd * INV180;              // ref: diff/180
            float gg = g * 10.0f;                // ref: g*BINS
            int idx  = (int)gg;                  // gg>=0 -> trunc == floor
            idx = min(max(idx, 0), BINS - 1);
            float ls = (ad < 1.0f) ? (0.5f * d * d) : (ad - 0.5f);  // smooth L1, mu=1
            float2 v = h[idx][t];
            v.x += 1.0f;
            v.y += ls;
            h[idx][t] = v;
        }
    }
    // scalar tail (n % 4), generic safety
    for (int i = (n4 << 2) + tid; i < n; i += stride) {
        float d  = pred[i] - target[i];
        float ad = fabsf(d);
        float wd = fminf(ad, 360.0f - ad);
        float g  = wd * INV180;
        float gg = g * 10.0f;
        int idx  = (int)gg;
        idx = min(max(idx, 0), BINS - 1);
        float ls = (ad < 1.0f) ? (0.5f * d * d) : (ad - 0.5f);
        float2 v = h[idx][t];
        v.x += 1.0f;
        v.y += ls;
        h[idx][t] = v;
    }
    __syncthreads();

    // Block epilogue: 160 threads, thread (r=t>>4, j=t&15) sums 16 columns
    // stride-16, then 16-lane shuffle tree. One float2 store per bin.
    if (t < 16 * BINS) {
        const int r = t >> 4;
        const int j = t & 15;
        float c = 0.0f, s = 0.0f;
#pragma unroll
        for (int k = 0; k < 16; ++k) {
            float2 v = h[r][j + 16 * k];
            c += v.x;
            s += v.y;
        }
#pragma unroll
        for (int off = 8; off > 0; off >>= 1) {
            c += __shfl_down(c, off, 16);
            s += __shfl_down(s, off, 16);
        }
        if (j == 0) part[r * gridDim.x + blockIdx.x] = make_float2(c, s);
    }
}

// ---------------------------------------------------------------------------
// Pass 2: reduce partials (one wave per bin, coalesced float2) + weight math.
// ---------------------------------------------------------------------------
__global__ __launch_bounds__(64 * BINS) void ghmr_reduce_final(
    const float2* __restrict__ part,
    const float*  __restrict__ acc_sum,
    float* __restrict__ out,
    float total, int nblk)
{
    const int w    = threadIdx.x >> 6;   // bin 0..9
    const int lane = threadIdx.x & 63;

    float csum = 0.0f, ssum = 0.0f;
    const float2* pw = part + (size_t)w * nblk;
    for (int i = lane; i < nblk; i += 64) {
        float2 v = pw[i];
        csum += v.x;
        ssum += v.y;
    }
#pragma unroll
    for (int off = 32; off > 0; off >>= 1) {
        csum += __shfl_down(csum, off, 64);
        ssum += __shfl_down(ssum, off, 64);
    }

    __shared__ float C[BINS];
    __shared__ float S[BINS];
    if (lane == 0) { C[w] = csum; S[w] = ssum; }
    __syncthreads();

    if (threadIdx.x == 0) {
        float acc_new[BINS];
        int n_nonempty = 0;
#pragma unroll
        for (int b = 0; b < BINS; ++b) {
            float cnt = C[b];
            bool ne = (cnt > 0.0f);
            acc_new[b] = ne ? (0.9f * acc_sum[b] + 0.1f * cnt) : acc_sum[b];
            n_nonempty += ne ? 1 : 0;
        }
        float n_safe = fmaxf((float)n_nonempty, 1.0f);

        double weighted = 0.0;
        double plain    = 0.0;
#pragma unroll
        for (int b = 0; b < BINS; ++b) {
            float wb = (acc_new[b] > 0.0f)
                           ? (total / (n_safe * fmaxf(acc_new[b], 1e-30f)))
                           : 0.0f;
            float wp = powf(wb, 0.75f);
            weighted += (double)S[b] * (double)wp;
            plain    += (double)S[b];
        }
        double res = ((n_nonempty > 0) ? weighted : plain) / (double)total;
        out[0] = (float)res;
    }
}

extern "C" void kernel_launch(void* const* d_in, const int* in_sizes, int n_in,
                              void* d_out, int out_size, void* d_ws, size_t ws_size,
                              hipStream_t stream) {
    const float* pred    = (const float*)d_in[0];
    const float* target  = (const float*)d_in[1];
    const float* acc_sum = (const float*)d_in[2];
    float* out = (float*)d_out;
    const int n = in_sizes[0];

    int nblk = GRID;
    size_t need = (size_t)BINS * (size_t)nblk * sizeof(float2);
    if (ws_size < need) {
        nblk = (int)(ws_size / ((size_t)BINS * sizeof(float2)));
        if (nblk < 1) nblk = 1;
    }

    float2* part = (float2*)d_ws;   // [BINS][nblk]

    ghmr_histo_kernel<<<nblk, BLOCK, 0, stream>>>(pred, target, part, n);
    ghmr_reduce_final<<<1, 64 * BINS, 0, stream>>>(part, acc_sum, out, (float)n, nblk);
}